// Round 4
// baseline (174.216 us; speedup 1.0000x reference)
//
#include <hip/hip_runtime.h>
#include <hip/hip_bf16.h>
#include <stdint.h>

// Shapes (fixed by the problem)
#define B_ROWS 16384
#define VDIM   16
#define SDIM   64
#define HDIM   512
#define KDIM   1024   // V*S
#define KP     1056   // KDIM + 16 bias cols + 16 zero pad

// ---- k1_gate LDS layout (M32 tile)
#define ASTR     1064                 // LDS x-row stride in u16 (1056+8 pad)
#define G_PLOG   68096                // 32*1064*2
#define G_LDS    (68096 + 8704)       // + plog [8][16][17] f32 = 76,800 B -> 2 blk/CU

// ---- k2_gemm LDS layout: double-buffered A-chunk [64][296] bf16
#define CSTR     296                  // 256 + 40 pad
#define BUFU16   (64 * CSTR)          // 18,944 u16 per buffer
#define GEMM_LDS (2 * BUFU16 * 2)     // 75,776 B -> 2 blocks/CU (151,552 <= 160K)

using bf16x8 = __attribute__((ext_vector_type(8))) __bf16;
using u16x8  = __attribute__((ext_vector_type(8))) unsigned short;
using u16x4  = __attribute__((ext_vector_type(4))) unsigned short;
using f32x4  = __attribute__((ext_vector_type(4))) float;

__device__ __forceinline__ unsigned short f2bf(float f) {
  unsigned int u = __builtin_bit_cast(unsigned int, f);
  u = (u + 0x7FFFu + ((u >> 16) & 1u)) >> 16;   // RNE
  return (unsigned short)u;
}
__device__ __forceinline__ float bf2f(unsigned short s) {
  return __builtin_bit_cast(float, (unsigned int)s << 16);
}

// ---------------------------------------------------------------------------
// K0 (merged):
//   blocks [0,66):   Bt = [W_cat ; bias ; 0]^T bf16 [HDIM][KP] via LDS-transpose
//   blocks [66,322): WcombT rows; block 322: bcomb.
__global__ __launch_bounds__(256) void k0_prep(
    const float* __restrict__ W, const float* __restrict__ bias,
    const float* __restrict__ Wsel, const float* __restrict__ bsel,
    unsigned short* __restrict__ Bt, unsigned short* __restrict__ WcombT,
    float* __restrict__ bcomb) {
  __shared__ float bm[HDIM];
  __shared__ float part[16][17];
  __shared__ unsigned short tile[32][264];
  const int t = threadIdx.x;
  if (blockIdx.x < 66) {
    const int k0 = (blockIdx.x >> 1) * 32;          // 0..1024 step 32
    const int n  = ((blockIdx.x & 1) << 8) + t;     // 0..511
    #pragma unroll 8
    for (int kk = 0; kk < 32; ++kk) {
      const int k = k0 + kk;
      float val;
      if (k < KDIM)            val = W[(size_t)k * HDIM + n];
      else if (k < KDIM + 16)  val = bias[(size_t)(k - KDIM) * HDIM + n];
      else                     val = 0.f;
      tile[kk][t] = f2bf(val);
    }
    __syncthreads();
    unsigned short* dst = Bt + (size_t)n * KP + k0;
    #pragma unroll
    for (int seg = 0; seg < 4; ++seg) {
      unsigned short o[8];
      #pragma unroll
      for (int jj = 0; jj < 8; ++jj) o[jj] = tile[seg * 8 + jj][t];
      *(u16x8*)(dst + seg * 8) = *(const u16x8*)o;
    }
    return;
  }
  const int bid = blockIdx.x - 66;     // 0..256
  if (bid < 256) {
    const int wave = t >> 6, lane = t & 63;
    const int k = bid * 4 + wave;
    const float* wr = W + (size_t)k * HDIM;
    float s[16];
    #pragma unroll
    for (int v = 0; v < 16; ++v) s[v] = 0.f;
    #pragma unroll
    for (int j = 0; j < 8; ++j) {
      const int h = lane + 64 * j;
      const float a = wr[h];
      const float4* wl = (const float4*)(Wsel + h * 16);
      const float4 q0 = wl[0], q1 = wl[1], q2 = wl[2], q3 = wl[3];
      s[0]  = fmaf(a, q0.x, s[0]);  s[1]  = fmaf(a, q0.y, s[1]);
      s[2]  = fmaf(a, q0.z, s[2]);  s[3]  = fmaf(a, q0.w, s[3]);
      s[4]  = fmaf(a, q1.x, s[4]);  s[5]  = fmaf(a, q1.y, s[5]);
      s[6]  = fmaf(a, q1.z, s[6]);  s[7]  = fmaf(a, q1.w, s[7]);
      s[8]  = fmaf(a, q2.x, s[8]);  s[9]  = fmaf(a, q2.y, s[9]);
      s[10] = fmaf(a, q2.z, s[10]); s[11] = fmaf(a, q2.w, s[11]);
      s[12] = fmaf(a, q3.x, s[12]); s[13] = fmaf(a, q3.y, s[13]);
      s[14] = fmaf(a, q3.z, s[14]); s[15] = fmaf(a, q3.w, s[15]);
    }
    #pragma unroll
    for (int off = 32; off > 0; off >>= 1) {
      #pragma unroll
      for (int v = 0; v < 16; ++v) s[v] += __shfl_xor(s[v], off, 64);
    }
    float mine = 0.f;
    #pragma unroll
    for (int v = 0; v < 16; ++v) mine = (lane == v) ? s[v] : mine;
    if (lane < 16) WcombT[lane * KDIM + k] = f2bf(mine * (1.f / 16.f));
  } else {
    for (int h = t; h < HDIM; h += 256) {
      float s = 0.f;
      #pragma unroll
      for (int v = 0; v < VDIM; ++v) s += bias[v * HDIM + h];
      bm[h] = s * (1.f / 16.f);
    }
    __syncthreads();
    int v = t & 15, sl = t >> 4;
    float s = 0.f;
    for (int h = sl * 32; h < sl * 32 + 32; ++h) s = fmaf(bm[h], Wsel[h * VDIM + v], s);
    part[sl][v] = s;
    __syncthreads();
    if (t < 16) {
      float s2 = bsel[t];
      #pragma unroll
      for (int i = 0; i < 16; ++i) s2 += part[i][t];
      bcomb[t] = s2;
    }
  }
}

// ---------------------------------------------------------------------------
// K1: gate only. M32 tile, grid 512, 2 blocks/CU. Stage bf16(x) -> LDS,
// logits via MFMA vs WcombT, softmax, write w[B][16] fp32. x loads CACHED
// (k2_gemm re-reads x from L3 right after).
__global__ __launch_bounds__(512, 4) void k1_gate(
    const float* __restrict__ x, const unsigned short* __restrict__ WcombT,
    const float* __restrict__ bcomb, float* __restrict__ wgate) {
  extern __shared__ unsigned short As[];          // [32][ASTR] bf16
  float* plog = (float*)((char*)As + G_PLOG);     // [8][16][17]

  const int t = threadIdx.x;
  const int rowb = blockIdx.x * 32;
  const int wave = t >> 6, lane = t & 63;
  const int mlane = lane & 15, quad = lane >> 4;

  // ---- Phase 1: stage bf16(x)
  {
    const int srow = t >> 4;            // 0..31
    const int sc = (t & 15) * 8;        // covers k = sc + i*128
    const float* xr = x + (size_t)(rowb + srow) * KDIM + sc;
    unsigned short* aw = As + srow * ASTR + sc;
    #pragma unroll
    for (int i = 0; i < 8; ++i) {
      const float4 a0 = *(const float4*)(xr + i * 128);
      const float4 a1 = *(const float4*)(xr + i * 128 + 4);
      u16x8 u;
      u[0] = f2bf(a0.x); u[1] = f2bf(a0.y); u[2] = f2bf(a0.z); u[3] = f2bf(a0.w);
      u[4] = f2bf(a1.x); u[5] = f2bf(a1.y); u[6] = f2bf(a1.z); u[7] = f2bf(a1.w);
      *(u16x8*)(aw + i * 128) = u;
    }
  }
  __syncthreads();

  // ---- Phase 2: partial logits. wave w: kh = w>>1 (K-quarter), rg = w&1
  {
    const int kh = wave >> 1, rg = wave & 1;
    const unsigned short* al = As + (rg * 16 + mlane) * ASTR + kh * 256 + quad * 8;
    const unsigned short* bl = WcombT + mlane * KDIM + kh * 256 + quad * 8;
    f32x4 acc = {0.f, 0.f, 0.f, 0.f};
    #pragma unroll
    for (int kt = 0; kt < 8; ++kt) {
      bf16x8 a = *(const bf16x8*)al; al += 32;
      bf16x8 b = *(const bf16x8*)bl; bl += 32;
      acc = __builtin_amdgcn_mfma_f32_16x16x32_bf16(a, b, acc, 0, 0, 0);
    }
    float* pl = plog + ((size_t)((kh * 2 + rg) * 16 + quad * 4) * 17 + mlane);
    #pragma unroll
    for (int r = 0; r < 4; ++r) pl[r * 17] = acc[r];
  }
  __syncthreads();

  // ---- Phase 3: softmax on 32 threads (row = t), write w to global
  if (t < 32) {
    const int rg = t >> 4, rr = t & 15;
    float l[16];
    float mx = -1e30f;
    #pragma unroll
    for (int v = 0; v < 16; ++v) {
      float s = bcomb[v];
      #pragma unroll
      for (int kq = 0; kq < 4; ++kq)
        s += plog[((size_t)((kq * 2 + rg) * 16 + rr)) * 17 + v];
      l[v] = s;
      mx = fmaxf(mx, s);
    }
    float s = 0.f;
    #pragma unroll
    for (int v = 0; v < 16; ++v) { l[v] = __expf(l[v] - mx); s += l[v]; }
    const float inv = 1.f / s;
    float* wo = wgate + (size_t)(rowb + t) * 16;
    #pragma unroll
    for (int q = 0; q < 4; ++q) {
      f32x4 o = {l[4*q] * inv, l[4*q+1] * inv, l[4*q+2] * inv, l[4*q+3] * inv};
      *(f32x4*)(wo + 4 * q) = o;
    }
  }
}

// ---------------------------------------------------------------------------
// K2: chunked double-buffered GEMM, N-SPLIT for occupancy.
// Grid 512 = 256 M-blocks x 2 N-halves (256 cols each) -> 2 blocks/CU,
// 4 waves/SIMD. Per wave: 64 rows x 32 cols, acc[4][2] (VGPR ~80 < 128 cap).
// Staging identical to R3 (top-of-chunk writes, dead-buffer slack);
// B register prefetch 4-deep over 2 pointers.
__global__ __launch_bounds__(512, 4) void k2_gemm(
    const float* __restrict__ x, const float* __restrict__ wgate,
    const unsigned short* __restrict__ Bt, float* __restrict__ C) {
  extern __shared__ unsigned short As[];   // [2][64][CSTR]
  const int t = threadIdx.x;
  const int rowb  = (blockIdx.x >> 1) * 64;
  const int nhalf = blockIdx.x & 1;
  const int wave = t >> 6, lane = t & 63;
  const int mlane = lane & 15, quad = lane >> 4;

  // ---- staging map: thread -> (row, 32 contiguous k within chunk)
  const int srow = t >> 3;            // 0..63
  const int sk   = (t & 7) * 32;      // chunk-local k base
  const float* xrow = x + (size_t)(rowb + srow) * KDIM + sk;
  const float* wrow = wgate + (size_t)(rowb + srow) * 16;
  const int vsub = (t & 7) >> 1;      // v = c*4 + vsub for chunk c
  const float w0 = wrow[vsub], w1 = wrow[4 + vsub],
              w2 = wrow[8 + vsub], w3 = wrow[12 + vsub];

  // ---- prologue: load + write chunk 0 into buf0
  f32x4 xr[8];
  #pragma unroll
  for (int i = 0; i < 8; ++i) xr[i] = *(const f32x4*)(xrow + i * 4);
  {
    unsigned short* dst = As + srow * CSTR + sk;
    #pragma unroll
    for (int s = 0; s < 4; ++s) {
      const f32x4 a = xr[2 * s], b2 = xr[2 * s + 1];
      u16x8 o;
      o[0] = f2bf(w0 * a[0]);  o[1] = f2bf(w0 * a[1]);
      o[2] = f2bf(w0 * a[2]);  o[3] = f2bf(w0 * a[3]);
      o[4] = f2bf(w0 * b2[0]); o[5] = f2bf(w0 * b2[1]);
      o[6] = f2bf(w0 * b2[2]); o[7] = f2bf(w0 * b2[3]);
      *(u16x8*)(dst + s * 8) = o;
    }
  }
  // issue chunk-1 x loads (land during chunk-0 MFMA)
  #pragma unroll
  for (int i = 0; i < 8; ++i) xr[i] = *(const f32x4*)(xrow + 256 + i * 4);

  // ---- B pointers (2 col-tiles) + 4-deep register prefetch (steps 0..3)
  const int colb = nhalf * 256 + wave * 32;
  const unsigned short* bp[2];
  #pragma unroll
  for (int j = 0; j < 2; ++j)
    bp[j] = Bt + (size_t)(colb + j * 16 + mlane) * KP + quad * 8;
  bf16x8 bvs[4][2];
  #pragma unroll
  for (int d = 0; d < 4; ++d)
    #pragma unroll
    for (int j = 0; j < 2; ++j)
      bvs[d][j] = *(const bf16x8*)(bp[j] + d * 32);
  #pragma unroll
  for (int j = 0; j < 2; ++j) bp[j] += 128;   // bp -> step 4

  __syncthreads();   // buf0 ready

  f32x4 acc[4][2];
  const f32x4 z = {0.f, 0.f, 0.f, 0.f};
  #pragma unroll
  for (int i = 0; i < 4; ++i)
    #pragma unroll
    for (int j = 0; j < 2; ++j) acc[i][j] = z;

  // ---- 4 main chunks, fully unrolled. Chunk c reads buf[c&1]; its top
  // writes buf[(c+1)&1] (dead since previous barrier).
  #pragma unroll
  for (int c = 0; c < 4; ++c) {
    // top-of-chunk staging writes
    if (c < 3) {
      const float ws = (c == 0) ? w1 : (c == 1) ? w2 : w3;
      unsigned short* dst = As + ((c + 1) & 1) * BUFU16 + srow * CSTR + sk;
      #pragma unroll
      for (int s = 0; s < 4; ++s) {
        const f32x4 a = xr[2 * s], b2 = xr[2 * s + 1];
        u16x8 o;
        o[0] = f2bf(ws * a[0]);  o[1] = f2bf(ws * a[1]);
        o[2] = f2bf(ws * a[2]);  o[3] = f2bf(ws * a[3]);
        o[4] = f2bf(ws * b2[0]); o[5] = f2bf(ws * b2[1]);
        o[6] = f2bf(ws * b2[2]); o[7] = f2bf(ws * b2[3]);
        *(u16x8*)(dst + s * 8) = o;
      }
      if (c < 2) {   // issue loads for chunk c+2
        #pragma unroll
        for (int i = 0; i < 8; ++i)
          xr[i] = *(const f32x4*)(xrow + (c + 2) * 256 + i * 4);
      }
    } else {
      // tail chunk (k 1024..1055) into buf0: A' = [w row bf16 ; zeros]
      const int j4 = (t & 7) * 4;   // 0..28
      u16x4 o;
      if (j4 < 16) {
        const f32x4 wv = *(const f32x4*)(wgate + (size_t)(rowb + srow) * 16 + j4);
        o[0] = f2bf(wv[0]); o[1] = f2bf(wv[1]); o[2] = f2bf(wv[2]); o[3] = f2bf(wv[3]);
      } else {
        o[0] = 0; o[1] = 0; o[2] = 0; o[3] = 0;
      }
      *(u16x4*)(As + srow * CSTR + j4) = o;
    }

    // 8 K-steps on buf[c&1]
    const unsigned short* buf = As + (c & 1) * BUFU16;
    #pragma unroll
    for (int kt = 0; kt < 8; ++kt) {
      const int ktg = c * 8 + kt;         // compile-time
      bf16x8 cur[2];
      #pragma unroll
      for (int j = 0; j < 2; ++j) cur[j] = bvs[kt & 3][j];
      if (ktg + 4 <= 32) {                // steps 0..32 exist
        #pragma unroll
        for (int j = 0; j < 2; ++j) { bvs[kt & 3][j] = *(const bf16x8*)bp[j]; bp[j] += 32; }
      }
      bf16x8 av[4];
      #pragma unroll
      for (int i = 0; i < 4; ++i)
        av[i] = *(const bf16x8*)(buf + (i * 16 + mlane) * CSTR + kt * 32 + quad * 8);
      #pragma unroll
      for (int i = 0; i < 4; ++i)
        #pragma unroll
        for (int j = 0; j < 2; ++j)
          acc[i][j] = __builtin_amdgcn_mfma_f32_16x16x32_bf16(av[i], cur[j], acc[i][j], 0, 0, 0);
    }
    __syncthreads();
  }

  // ---- tail K-step: ktg = 32, slot 0 holds B step 32, A from buf0
  {
    bf16x8 av[4];
    #pragma unroll
    for (int i = 0; i < 4; ++i)
      av[i] = *(const bf16x8*)(As + (i * 16 + mlane) * CSTR + quad * 8);
    #pragma unroll
    for (int i = 0; i < 4; ++i)
      #pragma unroll
      for (int j = 0; j < 2; ++j)
        acc[i][j] = __builtin_amdgcn_mfma_f32_16x16x32_bf16(av[i], bvs[0][j], acc[i][j], 0, 0, 0);
  }

  // ---- epilogue: C/D layout col=lane&15, row=quad*4+reg  [m89/m91]
  #pragma unroll
  for (int i = 0; i < 4; ++i)
    #pragma unroll
    for (int j = 0; j < 2; ++j)
      #pragma unroll
      for (int r = 0; r < 4; ++r) {
        const size_t row = (size_t)rowb + i * 16 + quad * 4 + r;
        const int col = colb + j * 16 + mlane;
        __builtin_nontemporal_store(acc[i][j][r], &C[row * HDIM + col]);
      }
}

// ---------------------------------------------------------------------------
extern "C" void kernel_launch(void* const* d_in, const int* in_sizes, int n_in,
                              void* d_out, int out_size, void* d_ws, size_t ws_size,
                              hipStream_t stream) {
  const float* x    = (const float*)d_in[0];   // [B, V, S] = [16384][1024] flat
  const float* W    = (const float*)d_in[1];   // [V, S, H] = [1024][512] flat
  const float* bias = (const float*)d_in[2];   // [V, H]
  const float* Wsel = (const float*)d_in[3];   // [H, V]
  const float* bsel = (const float*)d_in[4];   // [V]
  float* out = (float*)d_out;                  // [B, H] fp32

  char* ws = (char*)d_ws;
  unsigned short* Bt     = (unsigned short*)(ws);            // 512*1056*2 = 1,081,344 B
  unsigned short* WcombT = (unsigned short*)(ws + 1081344);  // 16*1024*2  =    32,768 B
  float*          bcomb  = (float*)(ws + 1114112);           // 16*4 (padded to 256)
  float*          wgate  = (float*)(ws + 1114368);           // 16384*16*4 = 1,048,576 B

  static int lds_set = 0;
  if (!lds_set) {
    hipFuncSetAttribute((const void*)k1_gate,
                        hipFuncAttributeMaxDynamicSharedMemorySize, G_LDS);
    hipFuncSetAttribute((const void*)k2_gemm,
                        hipFuncAttributeMaxDynamicSharedMemorySize, GEMM_LDS);
    lds_set = 1;
  }

  k0_prep<<<323, 256, 0, stream>>>(W, bias, Wsel, bsel, Bt, WcombT, bcomb);
  k1_gate<<<512, 512, G_LDS, stream>>>(x, WcombT, bcomb, wgate);
  k2_gemm<<<512, 512, GEMM_LDS, stream>>>(x, wgate, Bt, out);
}

// Round 6
// 165.511 us; speedup vs baseline: 1.0526x; 1.0526x over previous
//
#include <hip/hip_runtime.h>
#include <hip/hip_bf16.h>
#include <stdint.h>

// Shapes (fixed by the problem)
#define B_ROWS 16384
#define VDIM   16
#define SDIM   64
#define HDIM   512
#define KDIM   1024   // V*S
#define KP2    1088   // KDIM + 16 w-cols + 48 zero pad = 17*64

// ---- k1_gate LDS layout (M32 tile)
#define ASTR     1064                 // LDS x-row stride in u16 (1056+8 pad)
#define G_PLOG   68096                // 32*1064*2
#define G_WLDS   (68096 + 8704)       // + plog [8][16][17] f32
#define G_LDS    (68096 + 8704 + 2048) // + wlds [32][16] f32 = 78,848 B -> 2 blk/CU

using bf16x8 = __attribute__((ext_vector_type(8))) __bf16;
using u16x8  = __attribute__((ext_vector_type(8))) unsigned short;
using f32x4  = __attribute__((ext_vector_type(4))) float;

__device__ __forceinline__ unsigned short f2bf(float f) {
  unsigned int u = __builtin_bit_cast(unsigned int, f);
  u = (u + 0x7FFFu + ((u >> 16) & 1u)) >> 16;   // RNE
  return (unsigned short)u;
}
__device__ __forceinline__ float bf2f(unsigned short s) {
  return __builtin_bit_cast(float, (unsigned int)s << 16);
}

// async global->LDS, 16B per lane. LDS dest = wave-uniform base + lane*16.
// AS3 pointer via 32-bit truncation of the flat LDS address (CK pattern).
__device__ __forceinline__ void gl_lds16(const void* g, void* l) {
  __builtin_amdgcn_global_load_lds(
      (const __attribute__((address_space(1))) unsigned int*)(uintptr_t)g,
      (__attribute__((address_space(3))) unsigned int*)(unsigned int)(uintptr_t)l,
      16, 0, 0);
}

// ---------------------------------------------------------------------------
// K0 (merged):
//   blocks [0,68):   Bt = [W_cat ; bias ; 0]^T bf16 [HDIM][KP2] via LDS-transpose
//   blocks [68,324): WcombT rows; block 324: bcomb.
__global__ __launch_bounds__(256) void k0_prep(
    const float* __restrict__ W, const float* __restrict__ bias,
    const float* __restrict__ Wsel, const float* __restrict__ bsel,
    unsigned short* __restrict__ Bt, unsigned short* __restrict__ WcombT,
    float* __restrict__ bcomb) {
  __shared__ float bm[HDIM];
  __shared__ float part[16][17];
  __shared__ unsigned short tile[32][264];
  const int t = threadIdx.x;
  if (blockIdx.x < 68) {
    const int k0 = (blockIdx.x >> 1) * 32;          // 0..1056 step 32
    const int n  = ((blockIdx.x & 1) << 8) + t;     // 0..511
    #pragma unroll 8
    for (int kk = 0; kk < 32; ++kk) {
      const int k = k0 + kk;
      float val;
      if (k < KDIM)            val = W[(size_t)k * HDIM + n];
      else if (k < KDIM + 16)  val = bias[(size_t)(k - KDIM) * HDIM + n];
      else                     val = 0.f;
      tile[kk][t] = f2bf(val);
    }
    __syncthreads();
    unsigned short* dst = Bt + (size_t)n * KP2 + k0;
    #pragma unroll
    for (int seg = 0; seg < 4; ++seg) {
      unsigned short o[8];
      #pragma unroll
      for (int jj = 0; jj < 8; ++jj) o[jj] = tile[seg * 8 + jj][t];
      *(u16x8*)(dst + seg * 8) = *(const u16x8*)o;
    }
    return;
  }
  const int bid = blockIdx.x - 68;     // 0..256
  if (bid < 256) {
    const int wave = t >> 6, lane = t & 63;
    const int k = bid * 4 + wave;
    const float* wr = W + (size_t)k * HDIM;
    float s[16];
    #pragma unroll
    for (int v = 0; v < 16; ++v) s[v] = 0.f;
    #pragma unroll
    for (int j = 0; j < 8; ++j) {
      const int h = lane + 64 * j;
      const float a = wr[h];
      const float4* wl = (const float4*)(Wsel + h * 16);
      const float4 q0 = wl[0], q1 = wl[1], q2 = wl[2], q3 = wl[3];
      s[0]  = fmaf(a, q0.x, s[0]);  s[1]  = fmaf(a, q0.y, s[1]);
      s[2]  = fmaf(a, q0.z, s[2]);  s[3]  = fmaf(a, q0.w, s[3]);
      s[4]  = fmaf(a, q1.x, s[4]);  s[5]  = fmaf(a, q1.y, s[5]);
      s[6]  = fmaf(a, q1.z, s[6]);  s[7]  = fmaf(a, q1.w, s[7]);
      s[8]  = fmaf(a, q2.x, s[8]);  s[9]  = fmaf(a, q2.y, s[9]);
      s[10] = fmaf(a, q2.z, s[10]); s[11] = fmaf(a, q2.w, s[11]);
      s[12] = fmaf(a, q3.x, s[12]); s[13] = fmaf(a, q3.y, s[13]);
      s[14] = fmaf(a, q3.z, s[14]); s[15] = fmaf(a, q3.w, s[15]);
    }
    #pragma unroll
    for (int off = 32; off > 0; off >>= 1) {
      #pragma unroll
      for (int v = 0; v < 16; ++v) s[v] += __shfl_xor(s[v], off, 64);
    }
    float mine = 0.f;
    #pragma unroll
    for (int v = 0; v < 16; ++v) mine = (lane == v) ? s[v] : mine;
    if (lane < 16) WcombT[lane * KDIM + k] = f2bf(mine * (1.f / 16.f));
  } else {
    for (int h = t; h < HDIM; h += 256) {
      float s = 0.f;
      #pragma unroll
      for (int v = 0; v < VDIM; ++v) s += bias[v * HDIM + h];
      bm[h] = s * (1.f / 16.f);
    }
    __syncthreads();
    int v = t & 15, sl = t >> 4;
    float s = 0.f;
    for (int h = sl * 32; h < sl * 32 + 32; ++h) s = fmaf(bm[h], Wsel[h * VDIM + v], s);
    part[sl][v] = s;
    __syncthreads();
    if (t < 16) {
      float s2 = bsel[t];
      #pragma unroll
      for (int i = 0; i < 16; ++i) s2 += part[i][t];
      bcomb[t] = s2;
    }
  }
}

// ---------------------------------------------------------------------------
// K1: gate + A' materialization for a slice of rows. M32 tile per block.
// Phases: stage bf16(x)->LDS (+reg copy) | logits MFMA vs WcombT | softmax ->
// wlds | write A' = bf16(w*x) [sliceRows][KP2] (cols 1024..1039 = w, rest 0).
// Ap is indexed slice-LOCAL; x is indexed globally via rowbase.
__global__ __launch_bounds__(512, 4) void k1_gate(
    const float* __restrict__ x, const unsigned short* __restrict__ WcombT,
    const float* __restrict__ bcomb, unsigned short* __restrict__ Ap,
    int rowbase) {
  extern __shared__ unsigned short As[];          // [32][ASTR] bf16
  float* plog = (float*)((char*)As + G_PLOG);     // [8][16][17]
  float* wlds = (float*)((char*)As + G_WLDS);     // [32][16]

  const int t = threadIdx.x;
  const int lrow0 = blockIdx.x * 32;              // slice-local
  const int grow0 = rowbase + lrow0;              // global
  const int wave = t >> 6, lane = t & 63;
  const int mlane = lane & 15, quad = lane >> 4;
  const int srow = t >> 4;              // 0..31
  const int sc = (t & 15) * 8;          // covers k = sc + i*128

  // ---- Phase 1: stage bf16(x); keep register copy
  u16x8 xreg[8];
  {
    const float* xr = x + (size_t)(grow0 + srow) * KDIM + sc;
    unsigned short* aw = As + srow * ASTR + sc;
    #pragma unroll
    for (int i = 0; i < 8; ++i) {
      const f32x4 a0 = __builtin_nontemporal_load((const f32x4*)(xr + i * 128));
      const f32x4 a1 = __builtin_nontemporal_load((const f32x4*)(xr + i * 128 + 4));
      u16x8 u;
      u[0] = f2bf(a0[0]); u[1] = f2bf(a0[1]); u[2] = f2bf(a0[2]); u[3] = f2bf(a0[3]);
      u[4] = f2bf(a1[0]); u[5] = f2bf(a1[1]); u[6] = f2bf(a1[2]); u[7] = f2bf(a1[3]);
      xreg[i] = u;
      *(u16x8*)(aw + i * 128) = u;
    }
  }
  __syncthreads();

  // ---- Phase 2: partial logits. wave w: kh = w>>1 (K-quarter), rg = w&1
  {
    const int kh = wave >> 1, rg = wave & 1;
    const unsigned short* al = As + (rg * 16 + mlane) * ASTR + kh * 256 + quad * 8;
    const unsigned short* bl = WcombT + mlane * KDIM + kh * 256 + quad * 8;
    f32x4 acc = {0.f, 0.f, 0.f, 0.f};
    #pragma unroll
    for (int kt = 0; kt < 8; ++kt) {
      bf16x8 a = *(const bf16x8*)al; al += 32;
      bf16x8 b = *(const bf16x8*)bl; bl += 32;
      acc = __builtin_amdgcn_mfma_f32_16x16x32_bf16(a, b, acc, 0, 0, 0);
    }
    float* pl = plog + ((size_t)((kh * 2 + rg) * 16 + quad * 4) * 17 + mlane);
    #pragma unroll
    for (int r = 0; r < 4; ++r) pl[r * 17] = acc[r];
  }
  __syncthreads();

  // ---- Phase 3: softmax on 32 threads (row = t) -> wlds
  if (t < 32) {
    const int rg = t >> 4, rr = t & 15;
    float l[16];
    float mx = -1e30f;
    #pragma unroll
    for (int v = 0; v < 16; ++v) {
      float s = bcomb[v];
      #pragma unroll
      for (int kq = 0; kq < 4; ++kq)
        s += plog[((size_t)((kq * 2 + rg) * 16 + rr)) * 17 + v];
      l[v] = s;
      mx = fmaxf(mx, s);
    }
    float s = 0.f;
    #pragma unroll
    for (int v = 0; v < 16; ++v) { l[v] = __expf(l[v] - mx); s += l[v]; }
    const float inv = 1.f / s;
    float* wo = wlds + t * 16;
    #pragma unroll
    for (int v = 0; v < 16; ++v) wo[v] = l[v] * inv;
  }
  __syncthreads();

  // ---- Phase 4: write A' = bf16(w * x) + tail to global (coalesced 16B)
  {
    float wv[16];
    const f32x4* wq = (const f32x4*)(wlds + srow * 16);
    #pragma unroll
    for (int q = 0; q < 4; ++q) {
      const f32x4 f = wq[q];
      wv[4 * q + 0] = f[0]; wv[4 * q + 1] = f[1];
      wv[4 * q + 2] = f[2]; wv[4 * q + 3] = f[3];
    }
    const int vbase = (t & 15) >> 3;    // v = 2*i + vbase  (k = sc + 128*i)
    unsigned short* aw = Ap + (size_t)(lrow0 + srow) * KP2 + sc;
    #pragma unroll
    for (int i = 0; i < 8; ++i) {
      const float w = wv[2 * i + vbase];
      const u16x8 a = xreg[i];
      u16x8 o;
      #pragma unroll
      for (int j = 0; j < 8; ++j) o[j] = f2bf(w * bf2f(a[j]));
      *(u16x8*)(aw + i * 128) = o;
    }
    // tail: cols 1024..1039 = bf16(w), 1040..1087 = 0
    const int seg = t & 15;
    if (seg < 8) {
      u16x8 o;
      #pragma unroll
      for (int jj = 0; jj < 8; ++jj) {
        const int c = seg * 8 + jj;     // 0..63
        o[jj] = (c < 16) ? f2bf(wv[c]) : (unsigned short)0;
      }
      *(u16x8*)(Ap + (size_t)(lrow0 + srow) * KP2 + KDIM + seg * 8) = o;
    }
  }
}

// ---------------------------------------------------------------------------
// K2: pure bf16 GEMM, m97 structure. C[slice][512] = A'[slice][1088] x Bt^T.
// 128x128 tile, 256 threads (4 waves, 2x2), BK=64, 17 K-steps.
// A/B tiles staged via global_load_lds width-16 (linear LDS, zero VALU),
// 2-barrier K-loop, acc[4][4] per wave. Bijective XCD swizzle (m204).
__global__ __launch_bounds__(256) void k2_gemm(
    const unsigned short* __restrict__ Ap, const unsigned short* __restrict__ Bt,
    float* __restrict__ C, int rowbase) {
  __shared__ unsigned short As[8192];   // [128][64] bf16, linear
  __shared__ unsigned short Bs[8192];   // [128][64] bf16, linear

  const int t = threadIdx.x;
  // bijective XCD swizzle for any grid size (m204)
  const int nwg = gridDim.x;
  const int q = nwg >> 3, r = nwg & 7;
  const int xcd = blockIdx.x & 7, idx = blockIdx.x >> 3;
  const int bid = (xcd < r ? xcd * (q + 1) : r * (q + 1) + (xcd - r) * q) + idx;

  const int lrowb = (bid >> 2) * 128;          // slice-local A'/row base
  const int colb  = (bid & 3) * 128;
  const int wave = t >> 6, lane = t & 63;
  const int mlane = lane & 15, quad = lane >> 4;
  const int wr = wave >> 1, wc = wave & 1;

  // staging source pointers: wave stages LDS rows [wave*32, wave*32+32)
  const int l8 = lane >> 3, lk = (lane & 7) * 8;
  const unsigned short* asrc[4];
  const unsigned short* bsrc[4];
  #pragma unroll
  for (int i = 0; i < 4; ++i) {
    asrc[i] = Ap + (size_t)(lrowb + wave * 32 + i * 8 + l8) * KP2 + lk;
    bsrc[i] = Bt + (size_t)(colb + wave * 32 + i * 8 + l8) * KP2 + lk;
  }
  unsigned short* adst = As + wave * 2048;
  unsigned short* bdst = Bs + wave * 2048;

  f32x4 acc[4][4];
  const f32x4 z = {0.f, 0.f, 0.f, 0.f};
  #pragma unroll
  for (int i = 0; i < 4; ++i)
    #pragma unroll
    for (int j = 0; j < 4; ++j) acc[i][j] = z;

  #pragma unroll 1
  for (int kt = 0; kt < 17; ++kt) {
    // stage this K-tile (async, 16B/lane, LDS linear)
    #pragma unroll
    for (int i = 0; i < 4; ++i) gl_lds16(asrc[i], adst + i * 512);
    #pragma unroll
    for (int i = 0; i < 4; ++i) gl_lds16(bsrc[i], bdst + i * 512);
    #pragma unroll
    for (int i = 0; i < 4; ++i) { asrc[i] += 64; bsrc[i] += 64; }
    __syncthreads();   // drains vmcnt -> tiles visible

    #pragma unroll
    for (int ks = 0; ks < 2; ++ks) {
      bf16x8 av[4], bv[4];
      #pragma unroll
      for (int i = 0; i < 4; ++i)
        av[i] = *(const bf16x8*)(As + (wr * 64 + i * 16 + mlane) * 64 + ks * 32 + quad * 8);
      #pragma unroll
      for (int j = 0; j < 4; ++j)
        bv[j] = *(const bf16x8*)(Bs + (wc * 64 + j * 16 + mlane) * 64 + ks * 32 + quad * 8);
      #pragma unroll
      for (int i = 0; i < 4; ++i)
        #pragma unroll
        for (int j = 0; j < 4; ++j)
          acc[i][j] = __builtin_amdgcn_mfma_f32_16x16x32_bf16(av[i], bv[j], acc[i][j], 0, 0, 0);
    }
    __syncthreads();   // tile consumed, safe to overwrite
  }

  // ---- epilogue: C/D layout col=lane&15, row=quad*4+reg  [m89/m91]
  #pragma unroll
  for (int i = 0; i < 4; ++i)
    #pragma unroll
    for (int j = 0; j < 4; ++j)
      #pragma unroll
      for (int r2 = 0; r2 < 4; ++r2) {
        const size_t row = (size_t)rowbase + lrowb + wr * 64 + i * 16 + quad * 4 + r2;
        const int col = colb + wc * 64 + j * 16 + mlane;
        __builtin_nontemporal_store(acc[i][j][r2], &C[row * HDIM + col]);
      }
}

// ---------------------------------------------------------------------------
extern "C" void kernel_launch(void* const* d_in, const int* in_sizes, int n_in,
                              void* d_out, int out_size, void* d_ws, size_t ws_size,
                              hipStream_t stream) {
  const float* x    = (const float*)d_in[0];   // [B, V, S] = [16384][1024] flat
  const float* W    = (const float*)d_in[1];   // [V, S, H] = [1024][512] flat
  const float* bias = (const float*)d_in[2];   // [V, H]
  const float* Wsel = (const float*)d_in[3];   // [H, V]
  const float* bsel = (const float*)d_in[4];   // [V]
  float* out = (float*)d_out;                  // [B, H] fp32

  char* ws = (char*)d_ws;
  unsigned short* Bt     = (unsigned short*)(ws);            // 512*1088*2 = 1,114,112 B
  unsigned short* WcombT = (unsigned short*)(ws + 1114112);  // 16*1024*2  =    32,768 B
  float*          bcomb  = (float*)(ws + 1146880);           // 16*4 (padded to 256)
  unsigned short* Ap     = (unsigned short*)(ws + 1147136);  // sliceRows*1088*2

  // ---- size A' slice by the ACTUAL workspace (R5 failure suspect: overflow)
  const size_t fixed = 1147136;
  size_t avail = (ws_size > fixed) ? (ws_size - fixed) : 0;
  size_t maxRows = avail / (KP2 * 2);
  int sliceRows = (int)((maxRows / 128) * 128);
  if (sliceRows > B_ROWS) sliceRows = B_ROWS;
  if (sliceRows < 128) sliceRows = 128;   // ws >= ~1.5 MB (2.2 MB proven available)

  static int lds_set = 0;
  if (!lds_set) {
    hipFuncSetAttribute((const void*)k1_gate,
                        hipFuncAttributeMaxDynamicSharedMemorySize, G_LDS);
    lds_set = 1;
  }

  k0_prep<<<325, 256, 0, stream>>>(W, bias, Wsel, bsel, Bt, WcombT, bcomb);
  for (int r0 = 0; r0 < B_ROWS; r0 += sliceRows) {
    const int rows = (B_ROWS - r0 < sliceRows) ? (B_ROWS - r0) : sliceRows;
    k1_gate<<<rows / 32, 512, G_LDS, stream>>>(x, WcombT, bcomb, Ap, r0);
    k2_gemm<<<(rows / 128) * 4, 256, 0, stream>>>(Ap, Bt, out, r0);
  }
}

// Round 7
// 161.559 us; speedup vs baseline: 1.0783x; 1.0245x over previous
//
#include <hip/hip_runtime.h>
#include <hip/hip_bf16.h>
#include <stdint.h>

// Shapes (fixed by the problem)
#define B_ROWS 16384
#define VDIM   16
#define SDIM   64
#define HDIM   512
#define KDIM   1024   // V*S
#define KP2    1088   // KDIM + 16 w-cols + 48 zero pad = 17*64
#define BK     64     // GEMM K-step

// ---- k1_gate LDS layout (M32 tile)
#define ASTR     1064                 // LDS x-row stride in u16 (1056+8 pad)
#define G_PLOG   68096                // 32*1064*2
#define G_WLDS   (68096 + 8704)       // + plog [8][16][17] f32
#define G_LDS    (68096 + 8704 + 2048) // + wlds [32][16] f32 = 78,848 B -> 2 blk/CU

using bf16x8 = __attribute__((ext_vector_type(8))) __bf16;
using u16x8  = __attribute__((ext_vector_type(8))) unsigned short;
using f32x4  = __attribute__((ext_vector_type(4))) float;

__device__ __forceinline__ unsigned short f2bf(float f) {
  unsigned int u = __builtin_bit_cast(unsigned int, f);
  u = (u + 0x7FFFu + ((u >> 16) & 1u)) >> 16;   // RNE
  return (unsigned short)u;
}
__device__ __forceinline__ float bf2f(unsigned short s) {
  return __builtin_bit_cast(float, (unsigned int)s << 16);
}

// async global->LDS, 16B per lane. LDS dest = wave-uniform base + lane*16.
// AS3 pointer via 32-bit truncation of the flat LDS address (worked in R6).
__device__ __forceinline__ void gl_lds16(const void* g, void* l) {
  __builtin_amdgcn_global_load_lds(
      (const __attribute__((address_space(1))) unsigned int*)(uintptr_t)g,
      (__attribute__((address_space(3))) unsigned int*)(unsigned int)(uintptr_t)l,
      16, 0, 0);
}

// ---------------------------------------------------------------------------
// K0 (merged):
//   blocks [0,68):   Bt = [W_cat ; bias ; 0]^T bf16 [HDIM][KP2] via LDS-transpose
//   blocks [68,324): WcombT rows; block 324: bcomb.
__global__ __launch_bounds__(256) void k0_prep(
    const float* __restrict__ W, const float* __restrict__ bias,
    const float* __restrict__ Wsel, const float* __restrict__ bsel,
    unsigned short* __restrict__ Bt, unsigned short* __restrict__ WcombT,
    float* __restrict__ bcomb) {
  __shared__ float bm[HDIM];
  __shared__ float part[16][17];
  __shared__ unsigned short tile[32][264];
  const int t = threadIdx.x;
  if (blockIdx.x < 68) {
    const int k0 = (blockIdx.x >> 1) * 32;          // 0..1056 step 32
    const int n  = ((blockIdx.x & 1) << 8) + t;     // 0..511
    #pragma unroll 8
    for (int kk = 0; kk < 32; ++kk) {
      const int k = k0 + kk;
      float val;
      if (k < KDIM)            val = W[(size_t)k * HDIM + n];
      else if (k < KDIM + 16)  val = bias[(size_t)(k - KDIM) * HDIM + n];
      else                     val = 0.f;
      tile[kk][t] = f2bf(val);
    }
    __syncthreads();
    unsigned short* dst = Bt + (size_t)n * KP2 + k0;
    #pragma unroll
    for (int seg = 0; seg < 4; ++seg) {
      unsigned short o[8];
      #pragma unroll
      for (int jj = 0; jj < 8; ++jj) o[jj] = tile[seg * 8 + jj][t];
      *(u16x8*)(dst + seg * 8) = *(const u16x8*)o;
    }
    return;
  }
  const int bid = blockIdx.x - 68;     // 0..256
  if (bid < 256) {
    const int wave = t >> 6, lane = t & 63;
    const int k = bid * 4 + wave;
    const float* wr = W + (size_t)k * HDIM;
    float s[16];
    #pragma unroll
    for (int v = 0; v < 16; ++v) s[v] = 0.f;
    #pragma unroll
    for (int j = 0; j < 8; ++j) {
      const int h = lane + 64 * j;
      const float a = wr[h];
      const float4* wl = (const float4*)(Wsel + h * 16);
      const float4 q0 = wl[0], q1 = wl[1], q2 = wl[2], q3 = wl[3];
      s[0]  = fmaf(a, q0.x, s[0]);  s[1]  = fmaf(a, q0.y, s[1]);
      s[2]  = fmaf(a, q0.z, s[2]);  s[3]  = fmaf(a, q0.w, s[3]);
      s[4]  = fmaf(a, q1.x, s[4]);  s[5]  = fmaf(a, q1.y, s[5]);
      s[6]  = fmaf(a, q1.z, s[6]);  s[7]  = fmaf(a, q1.w, s[7]);
      s[8]  = fmaf(a, q2.x, s[8]);  s[9]  = fmaf(a, q2.y, s[9]);
      s[10] = fmaf(a, q2.z, s[10]); s[11] = fmaf(a, q2.w, s[11]);
      s[12] = fmaf(a, q3.x, s[12]); s[13] = fmaf(a, q3.y, s[13]);
      s[14] = fmaf(a, q3.z, s[14]); s[15] = fmaf(a, q3.w, s[15]);
    }
    #pragma unroll
    for (int off = 32; off > 0; off >>= 1) {
      #pragma unroll
      for (int v = 0; v < 16; ++v) s[v] += __shfl_xor(s[v], off, 64);
    }
    float mine = 0.f;
    #pragma unroll
    for (int v = 0; v < 16; ++v) mine = (lane == v) ? s[v] : mine;
    if (lane < 16) WcombT[lane * KDIM + k] = f2bf(mine * (1.f / 16.f));
  } else {
    for (int h = t; h < HDIM; h += 256) {
      float s = 0.f;
      #pragma unroll
      for (int v = 0; v < VDIM; ++v) s += bias[v * HDIM + h];
      bm[h] = s * (1.f / 16.f);
    }
    __syncthreads();
    int v = t & 15, sl = t >> 4;
    float s = 0.f;
    for (int h = sl * 32; h < sl * 32 + 32; ++h) s = fmaf(bm[h], Wsel[h * VDIM + v], s);
    part[sl][v] = s;
    __syncthreads();
    if (t < 16) {
      float s2 = bsel[t];
      #pragma unroll
      for (int i = 0; i < 16; ++i) s2 += part[i][t];
      bcomb[t] = s2;
    }
  }
}

// ---------------------------------------------------------------------------
// K1: gate + A' materialization for a slice of rows. M32 tile per block.
// (unchanged from R6 — near its 100 MB HBM floor)
__global__ __launch_bounds__(512, 4) void k1_gate(
    const float* __restrict__ x, const unsigned short* __restrict__ WcombT,
    const float* __restrict__ bcomb, unsigned short* __restrict__ Ap,
    int rowbase) {
  extern __shared__ unsigned short As[];          // [32][ASTR] bf16
  float* plog = (float*)((char*)As + G_PLOG);     // [8][16][17]
  float* wlds = (float*)((char*)As + G_WLDS);     // [32][16]

  const int t = threadIdx.x;
  const int lrow0 = blockIdx.x * 32;              // slice-local
  const int grow0 = rowbase + lrow0;              // global
  const int wave = t >> 6, lane = t & 63;
  const int mlane = lane & 15, quad = lane >> 4;
  const int srow = t >> 4;              // 0..31
  const int sc = (t & 15) * 8;          // covers k = sc + i*128

  // ---- Phase 1: stage bf16(x); keep register copy
  u16x8 xreg[8];
  {
    const float* xr = x + (size_t)(grow0 + srow) * KDIM + sc;
    unsigned short* aw = As + srow * ASTR + sc;
    #pragma unroll
    for (int i = 0; i < 8; ++i) {
      const f32x4 a0 = __builtin_nontemporal_load((const f32x4*)(xr + i * 128));
      const f32x4 a1 = __builtin_nontemporal_load((const f32x4*)(xr + i * 128 + 4));
      u16x8 u;
      u[0] = f2bf(a0[0]); u[1] = f2bf(a0[1]); u[2] = f2bf(a0[2]); u[3] = f2bf(a0[3]);
      u[4] = f2bf(a1[0]); u[5] = f2bf(a1[1]); u[6] = f2bf(a1[2]); u[7] = f2bf(a1[3]);
      xreg[i] = u;
      *(u16x8*)(aw + i * 128) = u;
    }
  }
  __syncthreads();

  // ---- Phase 2: partial logits. wave w: kh = w>>1 (K-quarter), rg = w&1
  {
    const int kh = wave >> 1, rg = wave & 1;
    const unsigned short* al = As + (rg * 16 + mlane) * ASTR + kh * 256 + quad * 8;
    const unsigned short* bl = WcombT + mlane * KDIM + kh * 256 + quad * 8;
    f32x4 acc = {0.f, 0.f, 0.f, 0.f};
    #pragma unroll
    for (int kt = 0; kt < 8; ++kt) {
      bf16x8 a = *(const bf16x8*)al; al += 32;
      bf16x8 b = *(const bf16x8*)bl; bl += 32;
      acc = __builtin_amdgcn_mfma_f32_16x16x32_bf16(a, b, acc, 0, 0, 0);
    }
    float* pl = plog + ((size_t)((kh * 2 + rg) * 16 + quad * 4) * 17 + mlane);
    #pragma unroll
    for (int r = 0; r < 4; ++r) pl[r * 17] = acc[r];
  }
  __syncthreads();

  // ---- Phase 3: softmax on 32 threads (row = t) -> wlds
  if (t < 32) {
    const int rg = t >> 4, rr = t & 15;
    float l[16];
    float mx = -1e30f;
    #pragma unroll
    for (int v = 0; v < 16; ++v) {
      float s = bcomb[v];
      #pragma unroll
      for (int kq = 0; kq < 4; ++kq)
        s += plog[((size_t)((kq * 2 + rg) * 16 + rr)) * 17 + v];
      l[v] = s;
      mx = fmaxf(mx, s);
    }
    float s = 0.f;
    #pragma unroll
    for (int v = 0; v < 16; ++v) { l[v] = __expf(l[v] - mx); s += l[v]; }
    const float inv = 1.f / s;
    float* wo = wlds + t * 16;
    #pragma unroll
    for (int v = 0; v < 16; ++v) wo[v] = l[v] * inv;
  }
  __syncthreads();

  // ---- Phase 4: write A' = bf16(w * x) + tail to global (coalesced 16B)
  {
    float wv[16];
    const f32x4* wq = (const f32x4*)(wlds + srow * 16);
    #pragma unroll
    for (int q = 0; q < 4; ++q) {
      const f32x4 f = wq[q];
      wv[4 * q + 0] = f[0]; wv[4 * q + 1] = f[1];
      wv[4 * q + 2] = f[2]; wv[4 * q + 3] = f[3];
    }
    const int vbase = (t & 15) >> 3;    // v = 2*i + vbase  (k = sc + 128*i)
    unsigned short* aw = Ap + (size_t)(lrow0 + srow) * KP2 + sc;
    #pragma unroll
    for (int i = 0; i < 8; ++i) {
      const float w = wv[2 * i + vbase];
      const u16x8 a = xreg[i];
      u16x8 o;
      #pragma unroll
      for (int j = 0; j < 8; ++j) o[j] = f2bf(w * bf2f(a[j]));
      *(u16x8*)(aw + i * 128) = o;
    }
    // tail: cols 1024..1039 = bf16(w), 1040..1087 = 0
    const int seg = t & 15;
    if (seg < 8) {
      u16x8 o;
      #pragma unroll
      for (int jj = 0; jj < 8; ++jj) {
        const int c = seg * 8 + jj;     // 0..63
        o[jj] = (c < 16) ? f2bf(wv[c]) : (unsigned short)0;
      }
      *(u16x8*)(Ap + (size_t)(lrow0 + srow) * KP2 + KDIM + seg * 8) = o;
    }
  }
}

// ---------------------------------------------------------------------------
// K2 v2: pure bf16 GEMM, T3 minimal 2-phase pipeline (counted vmcnt).
// 128x128 tile, 256 threads, BK=64, 17 K-steps, DOUBLE-BUFFERED LDS (64 KB).
// Per step: issue stage(kt+1) -> compute buf(kt) (32 MFMA) -> vmcnt(0) +
// raw s_barrier. Prefetch loads fly during the whole MFMA phase instead of
// being drained by __syncthreads before compute (R6's exposed-latency bug).
__global__ __launch_bounds__(256) void k2_gemm(
    const unsigned short* __restrict__ Ap, const unsigned short* __restrict__ Bt,
    float* __restrict__ C, int rowbase) {
  __shared__ unsigned short As[2][128 * BK];   // 2 x 16 KB
  __shared__ unsigned short Bs[2][128 * BK];   // 2 x 16 KB

  const int t = threadIdx.x;
  // bijective XCD swizzle for any grid size (m204)
  const int nwg = gridDim.x;
  const int q = nwg >> 3, r = nwg & 7;
  const int xcd = blockIdx.x & 7, idx = blockIdx.x >> 3;
  const int bid = (xcd < r ? xcd * (q + 1) : r * (q + 1) + (xcd - r) * q) + idx;

  const int lrowb = (bid >> 2) * 128;          // slice-local row base
  const int colb  = (bid & 3) * 128;
  const int wave = t >> 6, lane = t & 63;
  const int mlane = lane & 15, quad = lane >> 4;
  const int wr = wave >> 1, wc = wave & 1;

  // staging: wave stages LDS rows [wave*32, wave*32+32) of A and B tiles.
  // gl_lds writes base + lane*16B: row = i*8 + lane/8, col = (lane&7)*8 ->
  // linear [128][64] row-major. Global src pre-offset to match.
  const int l8 = lane >> 3, lk = (lane & 7) * 8;
  const unsigned short* asrc[4];
  const unsigned short* bsrc[4];
  #pragma unroll
  for (int i = 0; i < 4; ++i) {
    asrc[i] = Ap + (size_t)(lrowb + wave * 32 + i * 8 + l8) * KP2 + lk;
    bsrc[i] = Bt + (size_t)(colb + wave * 32 + i * 8 + l8) * KP2 + lk;
  }
  const int ldst = (wave * 32) * BK;   // u16 offset of this wave's region

  // ---- prologue: stage tile 0 into buf0, full drain once
  #pragma unroll
  for (int i = 0; i < 4; ++i) gl_lds16(asrc[i], &As[0][ldst + i * 8 * BK]);
  #pragma unroll
  for (int i = 0; i < 4; ++i) gl_lds16(bsrc[i], &Bs[0][ldst + i * 8 * BK]);
  #pragma unroll
  for (int i = 0; i < 4; ++i) { asrc[i] += BK; bsrc[i] += BK; }
  asm volatile("s_waitcnt vmcnt(0)" ::: "memory");
  __builtin_amdgcn_s_barrier();
  __builtin_amdgcn_sched_barrier(0);

  f32x4 acc[4][4];
  const f32x4 z = {0.f, 0.f, 0.f, 0.f};
  #pragma unroll
  for (int i = 0; i < 4; ++i)
    #pragma unroll
    for (int j = 0; j < 4; ++j) acc[i][j] = z;

  #pragma unroll 1
  for (int kt = 0; kt < 17; ++kt) {
    const int cur = kt & 1;
    // issue next-tile stage (writes buf cur^1 — dead since last barrier)
    if (kt < 16) {
      #pragma unroll
      for (int i = 0; i < 4; ++i) gl_lds16(asrc[i], &As[cur ^ 1][ldst + i * 8 * BK]);
      #pragma unroll
      for (int i = 0; i < 4; ++i) gl_lds16(bsrc[i], &Bs[cur ^ 1][ldst + i * 8 * BK]);
      #pragma unroll
      for (int i = 0; i < 4; ++i) { asrc[i] += BK; bsrc[i] += BK; }
    }
    // compute current tile (loads for kt+1 remain in flight underneath)
    #pragma unroll
    for (int ks = 0; ks < 2; ++ks) {
      bf16x8 av[4], bv[4];
      #pragma unroll
      for (int i = 0; i < 4; ++i)
        av[i] = *(const bf16x8*)(&As[cur][(wr * 64 + i * 16 + mlane) * BK + ks * 32 + quad * 8]);
      #pragma unroll
      for (int j = 0; j < 4; ++j)
        bv[j] = *(const bf16x8*)(&Bs[cur][(wc * 64 + j * 16 + mlane) * BK + ks * 32 + quad * 8]);
      #pragma unroll
      for (int i = 0; i < 4; ++i)
        #pragma unroll
        for (int j = 0; j < 4; ++j)
          acc[i][j] = __builtin_amdgcn_mfma_f32_16x16x32_bf16(av[i], bv[j], acc[i][j], 0, 0, 0);
    }
    // end of step: pin reads above, drain prefetch, one barrier
    __builtin_amdgcn_sched_barrier(0);
    asm volatile("s_waitcnt vmcnt(0)" ::: "memory");
    __builtin_amdgcn_s_barrier();
    __builtin_amdgcn_sched_barrier(0);
  }

  // ---- epilogue: C/D layout col=lane&15, row=quad*4+reg  [m89/m91]
  #pragma unroll
  for (int i = 0; i < 4; ++i)
    #pragma unroll
    for (int j = 0; j < 4; ++j)
      #pragma unroll
      for (int r2 = 0; r2 < 4; ++r2) {
        const size_t row = (size_t)rowbase + lrowb + wr * 64 + i * 16 + quad * 4 + r2;
        const int col = colb + wc * 64 + j * 16 + mlane;
        __builtin_nontemporal_store(acc[i][j][r2], &C[row * HDIM + col]);
      }
}

// ---------------------------------------------------------------------------
extern "C" void kernel_launch(void* const* d_in, const int* in_sizes, int n_in,
                              void* d_out, int out_size, void* d_ws, size_t ws_size,
                              hipStream_t stream) {
  const float* x    = (const float*)d_in[0];   // [B, V, S] = [16384][1024] flat
  const float* W    = (const float*)d_in[1];   // [V, S, H] = [1024][512] flat
  const float* bias = (const float*)d_in[2];   // [V, H]
  const float* Wsel = (const float*)d_in[3];   // [H, V]
  const float* bsel = (const float*)d_in[4];   // [V]
  float* out = (float*)d_out;                  // [B, H] fp32

  char* ws = (char*)d_ws;
  unsigned short* Bt     = (unsigned short*)(ws);            // 512*1088*2 = 1,114,112 B
  unsigned short* WcombT = (unsigned short*)(ws + 1114112);  // 16*1024*2  =    32,768 B
  float*          bcomb  = (float*)(ws + 1146880);           // 16*4 (padded to 256)
  unsigned short* Ap     = (unsigned short*)(ws + 1147136);  // sliceRows*1088*2

  // size A' slice by actual workspace (R6 counters: ws ~268 MB -> one slice)
  const size_t fixed = 1147136;
  size_t avail = (ws_size > fixed) ? (ws_size - fixed) : 0;
  size_t maxRows = avail / (KP2 * 2);
  int sliceRows = (int)((maxRows / 128) * 128);
  if (sliceRows > B_ROWS) sliceRows = B_ROWS;
  if (sliceRows < 128) sliceRows = 128;

  static int lds_set = 0;
  if (!lds_set) {
    hipFuncSetAttribute((const void*)k1_gate,
                        hipFuncAttributeMaxDynamicSharedMemorySize, G_LDS);
    lds_set = 1;
  }

  k0_prep<<<325, 256, 0, stream>>>(W, bias, Wsel, bsel, Bt, WcombT, bcomb);
  for (int r0 = 0; r0 < B_ROWS; r0 += sliceRows) {
    const int rows = (B_ROWS - r0 < sliceRows) ? (B_ROWS - r0) : sliceRows;
    k1_gate<<<rows / 32, 512, G_LDS, stream>>>(x, WcombT, bcomb, Ap, r0);
    k2_gemm<<<(rows / 128) * 4, 256, 0, stream>>>(Ap, Bt, out, r0);
  }
}